// Round 13
// baseline (160.482 us; speedup 1.0000x reference)
//
#include <hip/hip_runtime.h>
#include <hip/hip_bf16.h>
#include <stdint.h>

typedef short bf16x8 __attribute__((ext_vector_type(8)));
typedef float f32x16 __attribute__((ext_vector_type(16)));

#define T 2048
#define KLEN 2049
#define DK 32
#define NCO 32
#define NCI 32
#define NB 32

#define GR 2216          // padded reversed row length (covers g up to 2192)
#define SREF 2055        // x[s] lives at g = SREF - s (xr); xrs[g] = xr[g+1]
#define WT_CH 257        // 8-wide d-chunks, d in [0,2056)
#define WT_ELEMS (NCI*WT_CH*NCO*8)
#define XR_ELEMS (NB*NCI*GR)

#define WT_OFF 0
#define XR_OFF (WT_ELEMS*2)
#define XRS_OFF (XR_OFF + XR_ELEMS*2)

#define CIB 528          // bytes per ci row: 33 x 16B granules (264 elems)
#define GPC 528          // real granules per parity copy (16 ci x 33)
#define GPCP 576         // padded to 9 x 64-chunks (no copy-straddle)
#define CPYB 9280        // parity-copy stride: >=GPCP*16, ==64 mod 128 (bank de-alias)
#define BUFB (2*CPYB)    // 18560 per window buffer
#define LDS_TOT (2*BUFB) // 37120 -> 4 blocks/CU; reduce (8KB) reuses buf0

// ------ kernel-generation: SIREN -> flipped, fragment-layout W (1 blk/8 d) --
__global__ __launch_bounds__(256) void gen_w(
    const float* __restrict__ rel_pos,
    const float* __restrict__ w1, const float* __restrict__ b1, const float* __restrict__ om1,
    const float* __restrict__ w2, const float* __restrict__ b2, const float* __restrict__ om2,
    const float* __restrict__ w3, const float* __restrict__ b3,
    uint16_t* __restrict__ Wt)
{
    __shared__ float h1s[8][32];
    __shared__ float h2s[8][32];
    int t = threadIdx.x;
    int dchunk = blockIdx.x;             // 0..256
    int dd = t >> 5, i = t & 31;
    int d = (dchunk << 3) + dd;
    float pos = (d < KLEN) ? rel_pos[2048 - d] : 0.f;
    h1s[dd][i] = sinf(om1[0] * (w1[i] * pos + b1[i]));
    __syncthreads();
    {
        float a = b2[i];
        #pragma unroll
        for (int j = 0; j < 32; ++j) a += w2[i*32 + j] * h1s[dd][j];
        h2s[dd][i] = sinf(om2[0] * a);
    }
    __syncthreads();
    for (int r = 0; r < 4; ++r) {
        int tt = t + (r << 8);
        int ci = tt >> 5, co = tt & 31;
        int coci = (co << 5) + ci;       // w3 row index (co*CIN + ci)
        float w3r[32];
        #pragma unroll
        for (int j = 0; j < 8; ++j)
            *(float4*)&w3r[j*4] = *(const float4*)&w3[coci*32 + j*4];
        float bb = b3[coci];
        union { uint16_t u[8]; uint4 qv; } pack;
        #pragma unroll
        for (int ddd = 0; ddd < 8; ++ddd) {
            float a = bb;
            #pragma unroll
            for (int j = 0; j < 32; ++j) a += w3r[j] * h2s[ddd][j];
            if (((dchunk << 3) + ddd) >= KLEN) a = 0.f;
            __hip_bfloat16 hv = __float2bfloat16(a);
            pack.u[ddd] = *(uint16_t*)&hv;
        }
        *(uint4*)&Wt[((ci*WT_CH + dchunk)*NCO + co) << 3] = pack.qv;
    }
}

// ---------------- x -> reversed, zero-padded bf16 (plus shifted copy) -------
__global__ __launch_bounds__(256) void gen_x(const float* __restrict__ x,
                                             uint16_t* __restrict__ xr,
                                             uint16_t* __restrict__ xrs)
{
    int idx = blockIdx.x*256 + threadIdx.x;
    if (idx >= NB*NCI*GR) return;
    int row = idx / GR;          // b*32+ci
    int g = idx - row*GR;
    int s = SREF - g;
    float v  = (s  >= 0 && s  < T) ? x[row*T + s]  : 0.f;
    int s2 = s - 1;              // value at g+1
    float v2 = (s2 >= 0 && s2 < T) ? x[row*T + s2] : 0.f;
    __hip_bfloat16 hv = __float2bfloat16(v);
    __hip_bfloat16 hv2 = __float2bfloat16(v2);
    xr[idx]  = *(uint16_t*)&hv;
    xrs[idx] = *(uint16_t*)&hv2;
}

// ---------------- out <- bias (conv halves atomically accumulate) ----------
__global__ __launch_bounds__(256) void init_out(const float* __restrict__ bias,
                                                float* __restrict__ out)
{
    int i = blockIdx.x*256 + threadIdx.x;   // NB*NCO*T = 2097152
    out[i] = bias[(i >> 11) & 31];
}

__device__ __forceinline__ void gld16(const uint16_t* g, char* l)
{
    typedef const __attribute__((address_space(1))) uint32_t GU;
    typedef __attribute__((address_space(3))) uint32_t LU;
    __builtin_amdgcn_global_load_lds((GU*)g, (LU*)l, 16, 0, 0);
}

// ---------------- causal conv: implicit-Toeplitz MFMA GEMM -------------------
// K=4 tau-chain, 128-elem k-windows, ci-HALVED blocks: block = (h, q, b),
// 256 thr / 4 waves, 16 ci per block (wave w: ci_local = cii*4 + w, cii<4).
// Grid 1024 = 4 blocks/CU; co-resident {q,q+8}x{h0,h1} = 34 half-units/CU
// (uniform). All chains start wi=0 -> synchronized Wt windows (L2-resident).
// Two halves combine via one atomicAdd each into bias-pre-initialized out.
__global__ __launch_bounds__(256, 4) void conv(
    const uint16_t* __restrict__ Wt, const uint16_t* __restrict__ xr,
    float* __restrict__ out)
{
    __shared__ uint4 lds4[LDS_TOT/16];
    char* ldsb = (char*)lds4;
    float* red = (float*)lds4;            // 8KB, overlaps buf0; barrier-protected
    int tid = threadIdx.x;
    int b = blockIdx.x & 31;
    int q = (blockIdx.x >> 5) & 15;
    int h = blockIdx.x >> 9;              // ci-half
    int th = (q < 8) ? (63 - (q << 2)) : ((q << 2) - 29);
    int nw = (th + 1) >> 2;               // 128-elem windows
    int g0base = 2016 - (th << 5);
    int w = tid >> 6, lane = tid & 63, n = lane & 31, hi = lane >> 5;
    int cig = w;                          // 0..3

    // staging: 1152 idx = 2 copies x 576 (528 real + 48 pad); 64-idx chunks,
    // wave-uniform LDS dest (linear), per-lane global source.
    int srcE[5], dstC[5];
    #pragma unroll
    for (int k = 0; k < 5; ++k) {
        int gi = tid + (k << 8);
        if (gi < 1152) {
            int cpy = gi >= GPCP;
            int j = gi - cpy*GPCP;
            dstC[k] = cpy*CPYB + (j << 4);
            if (j < GPC) {
                int cl = (j*1986) >> 16;     // j/33 (valid j<1056)
                int qq = j - cl*33;
                srcE[k] = cpy*XR_ELEMS + (b*NCI + (h << 4) + cl)*GR + (qq << 3);
            } else srcE[k] = 0;              // pad granule: safe dummy source
        } else { srcE[k] = 0; dstC[k] = -1; }
    }

    // B-read base: o = (39 - n + 8*hi) + 16*MM; byte = cl*CIB + par*CPYB + 2*(o-par)
    int obase = 39 - n + (hi << 3);
    int par = obase & 1;
    int bbb = cig*CIB + par*CPYB + ((obase - par) << 1);

    f32x16 acc0, acc1, acc2, acc3;
    #pragma unroll
    for (int r = 0; r < 16; ++r) { acc0[r]=0.f; acc1[r]=0.f; acc2[r]=0.f; acc3[r]=0.f; }

    #define STAGE(BUF, GOFF) { \
        _Pragma("unroll") \
        for (int k = 0; k < 5; ++k) \
            if (dstC[k] >= 0) gld16(xr + srcE[k] + (GOFF), (BUF) + dstC[k]); }

    // prologue: DMA window 0 into buf0
    STAGE(ldsb, g0base)
    __syncthreads();

    for (int wi = 0; wi < nw; ++wi) {
        int cur = wi & 1;
        if (wi + 1 < nw) {                   // DMA next window into other buffer
            char* bufn = ldsb + (cur ^ 1)*BUFB;
            int g0n = g0base + ((wi + 1) << 7);
            STAGE(bufn, g0n)
        }
        int dcw = wi << 4;
        const char* rbase = ldsb + cur*BUFB + bbb;

        #pragma unroll
        for (int cii = 0; cii < 4; ++cii) {
            int ci = (h << 4) + (cii << 2) + cig;
            const uint16_t* aB = Wt + (((ci*WT_CH + dcw + hi)*NCO + n) << 3);
            bf16x8 av0 = *(const bf16x8*)(aB);
            bf16x8 av1 = *(const bf16x8*)(aB + 512);
            bf16x8 av2 = *(const bf16x8*)(aB + 1024);
            bf16x8 av3 = *(const bf16x8*)(aB + 1536);
            bf16x8 av4 = *(const bf16x8*)(aB + 2048);
            bf16x8 av5 = *(const bf16x8*)(aB + 2560);
            bf16x8 av6 = *(const bf16x8*)(aB + 3072);
            bf16x8 av7 = *(const bf16x8*)(aB + 3584);
            const char* pbase = rbase + cii*(4*CIB);

            #define RDBB(MM) union { uint32_t u_[4]; bf16x8 v; } bb; { \
                const char* pp = pbase + ((MM) << 5); \
                bb.u_[0] = *(const uint32_t*)(pp); \
                bb.u_[1] = *(const uint32_t*)(pp + 4); \
                bb.u_[2] = *(const uint32_t*)(pp + 8); \
                bb.u_[3] = *(const uint32_t*)(pp + 12); }
            #define MF(AC, AV) AC = __builtin_amdgcn_mfma_f32_32x32x16_bf16(AV, bb.v, AC, 0,0,0);

            { RDBB(0)  MF(acc0, av0) }
            { RDBB(1)  MF(acc0, av1) }
            { RDBB(2)  MF(acc0, av2) MF(acc1, av0) }
            { RDBB(3)  MF(acc0, av3) MF(acc1, av1) }
            { RDBB(4)  MF(acc0, av4) MF(acc1, av2) MF(acc2, av0) }
            { RDBB(5)  MF(acc0, av5) MF(acc1, av3) MF(acc2, av1) }
            { RDBB(6)  MF(acc0, av6) MF(acc1, av4) MF(acc2, av2) MF(acc3, av0) }
            { RDBB(7)  MF(acc0, av7) MF(acc1, av5) MF(acc2, av3) MF(acc3, av1) }
            { RDBB(8)  MF(acc1, av6) MF(acc2, av4) MF(acc3, av2) }
            { RDBB(9)  MF(acc1, av7) MF(acc2, av5) MF(acc3, av3) }
            { RDBB(10) MF(acc2, av6) MF(acc3, av4) }
            { RDBB(11) MF(acc2, av7) MF(acc3, av5) }
            { RDBB(12) MF(acc3, av6) }
            { RDBB(13) MF(acc3, av7) }
            #undef MF
            #undef RDBB
        }
        __syncthreads();                 // drains DMA (vmcnt) + read/write fence
    }
    #undef STAGE

    // ---- reduce across 4 ci-waves + atomic epilogue, one delta at a time ----
    #pragma unroll
    for (int dlt = 0; dlt < 4; ++dlt) {
        f32x16 a = (dlt == 0) ? acc0 : (dlt == 1) ? acc1 : (dlt == 2) ? acc2 : acc3;
        __syncthreads();
        if (w < 2) {
            #pragma unroll
            for (int r = 0; r < 16; ++r)
                red[(w*16 + r)*64 + lane] = a[r];
        }
        __syncthreads();
        if (w >= 2) {
            #pragma unroll
            for (int r = 0; r < 16; ++r)
                red[((w-2)*16 + r)*64 + lane] += a[r];
        }
        __syncthreads();
        int t0 = (th - dlt) << 5;
        #pragma unroll
        for (int hh = 0; hh < 4; ++hh) {
            int e = tid + (hh << 8);
            int lane_e = e & 63;
            int reg = e >> 6;
            float s = red[(reg)*64 + lane_e] + red[(16 + reg)*64 + lane_e];
            int co = (reg & 3) + ((reg >> 2) << 3) + ((lane_e >> 5) << 2);
            int t = t0 + (lane_e & 31);
            atomicAdd(&out[(b*NCO + co)*T + t], s);
        }
    }
}

extern "C" void kernel_launch(void* const* d_in, const int* in_sizes, int n_in,
                              void* d_out, int out_size, void* d_ws, size_t ws_size,
                              hipStream_t stream)
{
    const float* x       = (const float*)d_in[0];
    const float* rel_pos = (const float*)d_in[1];
    const float* w1  = (const float*)d_in[2];
    const float* b1  = (const float*)d_in[3];
    const float* om1 = (const float*)d_in[4];
    const float* w2  = (const float*)d_in[5];
    const float* b2  = (const float*)d_in[6];
    const float* om2 = (const float*)d_in[7];
    const float* w3  = (const float*)d_in[8];
    const float* b3  = (const float*)d_in[9];
    const float* bias = (const float*)d_in[10];
    float* out = (float*)d_out;
    char* ws = (char*)d_ws;
    uint16_t* Wt  = (uint16_t*)(ws + WT_OFF);
    uint16_t* xrp = (uint16_t*)(ws + XR_OFF);
    uint16_t* xrs = (uint16_t*)(ws + XRS_OFF);

    hipLaunchKernelGGL(gen_w, dim3(WT_CH), dim3(256), 0, stream,
                       rel_pos, w1, b1, om1, w2, b2, om2, w3, b3, Wt);
    int n2 = NB*NCI*GR;
    hipLaunchKernelGGL(gen_x, dim3((n2+255)/256), dim3(256), 0, stream, x, xrp, xrs);
    hipLaunchKernelGGL(init_out, dim3(NB*NCO*T/256), dim3(256), 0, stream, bias, out);
    hipLaunchKernelGGL(conv, dim3(NB*16*2), dim3(256), 0, stream, Wt, xrp, out);
}